// Round 7
// baseline (169.638 us; speedup 1.0000x reference)
//
#include <hip/hip_runtime.h>

// Problem constants (B=64, T=4096, D=100, K=4, BETA=0.25)
#define D_DIM   100
#define K_CODES 4
#define RPB     64      // rows per block
#define TPB     256     // threads per block (4 waves)
#define PITCH   65      // f32 h-tile pitch (words)
#define N_ROWS  262144  // B*T
#define KP      128     // padded K for MFMA (4 k-tiles of 32)
#define NP      128     // padded N rows of W hi/lo storage
#define TAU     0.25    // d2 margin below which we recompute exactly (>=10x error bound)

typedef __attribute__((ext_vector_type(8))) __bf16 bf16x8;
typedef __attribute__((ext_vector_type(4))) float  f32x4;

// float -> bf16 bits, RNE (used in split_w; native casts used in hot kernel)
__device__ __forceinline__ unsigned short f2bf_rne(float f) {
    unsigned int u = __builtin_bit_cast(unsigned int, f);
    unsigned int r = u + 0x7fffu + ((u >> 16) & 1u);
    return (unsigned short)(r >> 16);
}
__device__ __forceinline__ float bf2f(unsigned short b) {
    unsigned int u = ((unsigned int)b) << 16;
    return __builtin_bit_cast(float, u);
}

// ---------------- pre-kernel: split W1 into padded bf16 hi/lo [NP][KP] ----------------
__global__ __launch_bounds__(256) void split_w_kernel(
    const float* __restrict__ W1,
    unsigned short* __restrict__ Whi, unsigned short* __restrict__ Wlo)
{
    int i = blockIdx.x * 256 + threadIdx.x;
    if (i >= NP * KP) return;
    int n = i / KP, k = i % KP;
    float w = (n < D_DIM && k < D_DIM) ? W1[n * D_DIM + k] : 0.0f;
    unsigned short hb = f2bf_rne(w);
    float lo = w - bf2f(hb);
    Whi[i] = hb;
    Wlo[i] = f2bf_rne(lo);
}

// ---------------- Fused: MFMA GEMM+ReLU -> LDS h-tile -> VQ -> writeout ----------------
// Block = 64 rows, 4 waves; wave owns 32 output cols. Layout verified R5/R6.
__global__ __launch_bounds__(TPB) void fused_kernel(
    const float* __restrict__ x,
    const unsigned short* __restrict__ Whi, const unsigned short* __restrict__ Wlo,
    const float* __restrict__ b1, const float* __restrict__ cb,
    const float* __restrict__ W1, const int* __restrict__ qflag,
    float* __restrict__ out_h, float* __restrict__ out_pay,
    float* __restrict__ out_aux, double* __restrict__ partials)
{
    // Union region: phase 1-2 = xhi/xlo bf16 staging (32 KB); phase 3+ = f32 h-tile (26 KB)
    __shared__ __align__(16) unsigned char smem[32768];
    __shared__ double d2s[K_CODES][RPB];
    __shared__ int    idxs[RPB];
    __shared__ unsigned long long flagmask;
    unsigned short* xhi = reinterpret_cast<unsigned short*>(smem);          // [64*128]
    unsigned short* xlo = xhi + RPB * KP;                                   // [64*128]
    float* ftile = reinterpret_cast<float*>(smem);                          // [100][65] h^T

    const int tid  = threadIdx.x;
    const int lane = tid & 63;
    const int wave = tid >> 6;
    const int blk  = blockIdx.x;
    const int rowBase = blk * RPB;
    const float* xg = x + (size_t)rowBase * D_DIM;
    const int qz = *qflag;   // grid-uniform

    // ---- B fragments (registers) + bias ----
    const int bcol0 = wave * 32;
    const int bn  = lane & 15;
    const int bk  = (lane >> 4) * 8;
    bf16x8 bh[2][4], bl[2][4];
    #pragma unroll
    for (int ct = 0; ct < 2; ++ct) {
        int n = bcol0 + ct * 16 + bn;
        #pragma unroll
        for (int kt = 0; kt < 4; ++kt) {
            int off = n * KP + kt * 32 + bk;
            bh[ct][kt] = *reinterpret_cast<const bf16x8*>(Whi + off);
            bl[ct][kt] = *reinterpret_cast<const bf16x8*>(Wlo + off);
        }
    }
    float bias[2];
    #pragma unroll
    for (int ct = 0; ct < 2; ++ct) {
        int n = bcol0 + ct * 16 + bn;
        bias[ct] = (n < D_DIM) ? b1[n] : 0.0f;
    }

    // ---- stage x: f32 -> hi/lo bf16 via native casts (cvt_pk-fusable) -> swizzled LDS ----
    for (int v = tid; v < RPB * 25; v += TPB) {
        float4 val = reinterpret_cast<const float4*>(xg)[v];
        int r = v / 25;
        int d = (v % 25) * 4;
        __bf16 hx = (__bf16)val.x, hy = (__bf16)val.y,
               hz = (__bf16)val.z, hw_ = (__bf16)val.w;
        __bf16 lx = (__bf16)(val.x - (float)hx), ly = (__bf16)(val.y - (float)hy),
               lz = (__bf16)(val.z - (float)hz), lw_ = (__bf16)(val.w - (float)hw_);
        ushort4 hv, lv;
        hv.x = __builtin_bit_cast(unsigned short, hx);
        hv.y = __builtin_bit_cast(unsigned short, hy);
        hv.z = __builtin_bit_cast(unsigned short, hz);
        hv.w = __builtin_bit_cast(unsigned short, hw_);
        lv.x = __builtin_bit_cast(unsigned short, lx);
        lv.y = __builtin_bit_cast(unsigned short, ly);
        lv.z = __builtin_bit_cast(unsigned short, lz);
        lv.w = __builtin_bit_cast(unsigned short, lw_);
        int byte = r * 256 + ((d * 2) ^ ((r & 7) << 4));
        *reinterpret_cast<ushort4*>(reinterpret_cast<char*>(xhi) + byte) = hv;
        *reinterpret_cast<ushort4*>(reinterpret_cast<char*>(xlo) + byte) = lv;
    }
    for (int v = tid; v < RPB * 7; v += TPB) {   // zero-pad k in [100,128)
        int r = v / 7;
        int c = v % 7;
        int byte = r * 256 + (((200 + c * 8)) ^ ((r & 7) << 4));
        ushort4 z = {0, 0, 0, 0};
        *reinterpret_cast<ushort4*>(reinterpret_cast<char*>(xhi) + byte) = z;
        *reinterpret_cast<ushort4*>(reinterpret_cast<char*>(xlo) + byte) = z;
    }
    __syncthreads();

    // ---- MFMA main: 4 row-tiles x 2 col-tiles x 4 k-tiles x 3 passes; acc kept live ----
    const int am = lane & 15;
    const int ak = (lane >> 4) * 8;
    f32x4 acc[4][2];
    #pragma unroll
    for (int rt = 0; rt < 4; ++rt) {
        const int mrow = rt * 16 + am;
        bf16x8 ah[4], al[4];
        #pragma unroll
        for (int kt = 0; kt < 4; ++kt) {
            int byte = mrow * 256 + (((kt * 32 + ak) * 2) ^ ((mrow & 7) << 4));
            ah[kt] = *reinterpret_cast<const bf16x8*>(reinterpret_cast<const char*>(xhi) + byte);
            al[kt] = *reinterpret_cast<const bf16x8*>(reinterpret_cast<const char*>(xlo) + byte);
        }
        #pragma unroll
        for (int ct = 0; ct < 2; ++ct) {
            f32x4 a = {0.f, 0.f, 0.f, 0.f};
            #pragma unroll
            for (int kt = 0; kt < 4; ++kt) {
                a = __builtin_amdgcn_mfma_f32_16x16x32_bf16(ah[kt], bl[ct][kt], a, 0, 0, 0);
                a = __builtin_amdgcn_mfma_f32_16x16x32_bf16(al[kt], bh[ct][kt], a, 0, 0, 0);
                a = __builtin_amdgcn_mfma_f32_16x16x32_bf16(ah[kt], bh[ct][kt], a, 0, 0, 0);
            }
            acc[rt][ct] = a;
        }
    }
    __syncthreads();   // all MFMA LDS reads done -> safe to overwrite smem with ftile

    // ---- bias+ReLU epilogue into LDS h^T tile ----
    #pragma unroll
    for (int rt = 0; rt < 4; ++rt) {
        int rb = rt * 16 + (lane >> 4) * 4;
        #pragma unroll
        for (int ct = 0; ct < 2; ++ct) {
            int n = bcol0 + ct * 16 + bn;
            if (n < D_DIM) {
                #pragma unroll
                for (int i = 0; i < 4; ++i)
                    ftile[n * PITCH + rb + i] = fmaxf(acc[rt][ct][i] + bias[ct], 0.0f);
            }
        }
    }
    __syncthreads();

    if (qz) {
        // ---- f64 distances: wave = code k, lane = row (R1-proven formulation) ----
        {
            const int k = __builtin_amdgcn_readfirstlane(wave & 3);
            const float* crow = cb + k * D_DIM;
            double s = 0.0;
            #pragma unroll
            for (int d = 0; d < D_DIM; ++d) {
                double dh = (double)ftile[d * PITCH + lane] - (double)crow[d];
                s = fma(dh, dh, s);
            }
            d2s[k][lane] = s;
        }
        __syncthreads();

        // ---- wave 0: tentative argmin + margin flag ----
        if (wave == 0) {
            double best = d2s[0][lane], second = 1e300;
            int bi = 0;
            #pragma unroll
            for (int k = 1; k < K_CODES; ++k) {
                double v = d2s[k][lane];
                if (v < best) { second = best; best = v; bi = k; }
                else if (v < second) { second = v; }
            }
            idxs[lane] = bi;
            unsigned long long m = __ballot((second - best) < TAU);
            if (lane == 0) flagmask = m;
        }
        __syncthreads();

        // ---- margin-flagged rows: wave-cooperative exact recompute (R6-proven) ----
        {
            unsigned long long m = flagmask;
            int i = 0;
            while (m) {
                int r = __ffsll((long long)m) - 1;
                m &= m - 1;
                if ((i & 3) == wave) {
                    const int e1 = lane;
                    const int e2 = 64 + lane;
                    const bool has2 = (e2 < D_DIM);
                    float z1 = b1[e1];
                    float z2 = has2 ? b1[e2] : 0.0f;
                    const float* xr  = x + (size_t)(rowBase + r) * D_DIM;
                    const float* w1r = W1 + e1 * D_DIM;
                    const float* w2r = W1 + (has2 ? e2 : 0) * D_DIM;
                    #pragma unroll
                    for (int d4 = 0; d4 < 25; ++d4) {
                        float4 xv = reinterpret_cast<const float4*>(xr)[d4];
                        float4 wa = reinterpret_cast<const float4*>(w1r)[d4];
                        z1 = fmaf(xv.x, wa.x, z1); z1 = fmaf(xv.y, wa.y, z1);
                        z1 = fmaf(xv.z, wa.z, z1); z1 = fmaf(xv.w, wa.w, z1);
                        float4 wb = reinterpret_cast<const float4*>(w2r)[d4];
                        z2 = fmaf(xv.x, wb.x, z2); z2 = fmaf(xv.y, wb.y, z2);
                        z2 = fmaf(xv.z, wb.z, z2); z2 = fmaf(xv.w, wb.w, z2);
                    }
                    float h1 = fmaxf(z1, 0.0f);
                    float h2 = fmaxf(z2, 0.0f);
                    double dk[K_CODES];
                    #pragma unroll
                    for (int k = 0; k < K_CODES; ++k) {
                        double p;
                        {
                            double dh = (double)h1 - (double)cb[k * D_DIM + e1];
                            p = dh * dh;
                        }
                        if (has2) {
                            double dh = (double)h2 - (double)cb[k * D_DIM + e2];
                            p = fma(dh, dh, p);
                        }
                        for (int off = 32; off > 0; off >>= 1)
                            p += __shfl_down(p, off);
                        dk[k] = p;
                    }
                    if (lane == 0) {
                        double best = dk[0];
                        int bi = 0;
                        #pragma unroll
                        for (int k = 1; k < K_CODES; ++k)
                            if (dk[k] < best) { best = dk[k]; bi = k; }
                        idxs[r] = bi;
                    }
                }
                ++i;
            }
        }
        __syncthreads();

        // ---- wave 0: payload + loss partial ----
        if (wave == 0) {
            int bi = idxs[lane];
            out_pay[rowBase + lane] = (float)bi;
            double d2min = d2s[bi][lane];
            for (int off = 32; off > 0; off >>= 1)
                d2min += __shfl_down(d2min, off);
            if (lane == 0) partials[blk] = d2min;
        }

        // ---- coalesced writeout: h (LDS transpose) + aux (codebook gather) ----
        float* hg = out_h + (size_t)rowBase * D_DIM;
        float* ag = out_aux + (size_t)rowBase * D_DIM;
        for (int v = tid; v < RPB * 25; v += TPB) {
            int r = v / 25;
            int d = (v % 25) * 4;
            float4 hv = make_float4(ftile[d * PITCH + r], ftile[(d + 1) * PITCH + r],
                                    ftile[(d + 2) * PITCH + r], ftile[(d + 3) * PITCH + r]);
            reinterpret_cast<float4*>(hg)[v] = hv;
            int bi = idxs[r];
            reinterpret_cast<float4*>(ag)[v] =
                reinterpret_cast<const float4*>(cb + bi * D_DIM + d)[0];
        }
    } else {
        // quantize==0 path (not exercised; deterministic)
        if (wave == 0) {
            out_pay[rowBase + lane] = 0.0f;
            if (lane == 0) partials[blk] = 0.0;
        }
        float* hg = out_h + (size_t)rowBase * D_DIM;
        float* ag = out_aux + (size_t)rowBase * D_DIM;
        for (int v = tid; v < RPB * 25; v += TPB) {
            int r = v / 25;
            int d = (v % 25) * 4;
            float4 hv = make_float4(ftile[d * PITCH + r], ftile[(d + 1) * PITCH + r],
                                    ftile[(d + 2) * PITCH + r], ftile[(d + 3) * PITCH + r]);
            reinterpret_cast<float4*>(hg)[v] = hv;
            reinterpret_cast<float4*>(ag)[v] = make_float4(0, 0, 0, 0);
        }
    }
}

// ---------------- deterministic final loss reduce ----------------
__global__ __launch_bounds__(256) void vq_final_kernel(
    const double* __restrict__ partials, int n, float* __restrict__ loss_out)
{
    __shared__ double sm[256];
    int tid = threadIdx.x;
    double s = 0.0;
    for (int i = tid; i < n; i += 256) s += partials[i];
    sm[tid] = s;
    __syncthreads();
    for (int off = 128; off > 0; off >>= 1) {
        if (tid < off) sm[tid] += sm[tid + off];
        __syncthreads();
    }
    if (tid == 0) {
        double mse = sm[0] / ((double)N_ROWS * (double)D_DIM);
        loss_out[0] = (float)(1.25 * mse);   // (1 + BETA) * mean((h-q)^2)
    }
}

extern "C" void kernel_launch(void* const* d_in, const int* in_sizes, int n_in,
                              void* d_out, int out_size, void* d_ws, size_t ws_size,
                              hipStream_t stream) {
    const float* x  = (const float*)d_in[0];
    const float* W1 = (const float*)d_in[1];
    const float* b1 = (const float*)d_in[2];
    const float* cb = (const float*)d_in[3];
    const int* qflag = (const int*)d_in[4];

    float* out = (float*)d_out;
    const int NR = in_sizes[0] / D_DIM;        // 262144 rows
    const int nblocks = NR / RPB;              // 4096

    float* out_h    = out;                                  // [NR*100]
    float* out_pay  = out + (size_t)NR * D_DIM;             // [NR]
    float* out_aux  = out_pay + NR;                         // [NR*100]
    float* out_loss = out_aux + (size_t)NR * D_DIM;         // [1]

    double* partials = (double*)d_ws;                       // 32 KB
    const size_t w_off = (size_t)nblocks * sizeof(double);
    unsigned short* Whi = (unsigned short*)((char*)d_ws + w_off);   // 32 KB
    unsigned short* Wlo = Whi + NP * KP;                            // 32 KB

    split_w_kernel<<<(NP * KP) / 256, 256, 0, stream>>>(W1, Whi, Wlo);
    fused_kernel<<<nblocks, TPB, 0, stream>>>(x, Whi, Wlo, b1, cb, W1, qflag,
                                              out_h, out_pay, out_aux, partials);
    vq_final_kernel<<<1, 256, 0, stream>>>(partials, nblocks, out_loss);
}

// Round 8
// 127.395 us; speedup vs baseline: 1.3316x; 1.3316x over previous
//
#include <hip/hip_runtime.h>

// Problem constants (B=64, T=4096, D=100, K=4, BETA=0.25)
#define D_DIM   100
#define K_CODES 4
#define RPB     64      // rows per block
#define TPB     256     // threads per block (4 waves)
#define PITCH   65      // f32 h^T-tile pitch (words)
#define N_ROWS  262144  // B*T
#define KP      128     // padded K for W hi/lo storage (4 k-tiles of 32)
#define NP      128     // padded N rows of W hi/lo storage
#define TAU     0.25    // d2 margin below which we recompute exactly

typedef __attribute__((ext_vector_type(8))) __bf16 bf16x8;
typedef __attribute__((ext_vector_type(4))) float  f32x4;

__device__ __forceinline__ unsigned short f2bf_rne(float f) {
    unsigned int u = __builtin_bit_cast(unsigned int, f);
    unsigned int r = u + 0x7fffu + ((u >> 16) & 1u);
    return (unsigned short)(r >> 16);
}
__device__ __forceinline__ float bf2f(unsigned short b) {
    unsigned int u = ((unsigned int)b) << 16;
    return __builtin_bit_cast(float, u);
}

// async global->LDS, 16B per lane: LDS dest = wave-uniform base + lane*16
__device__ __forceinline__ void load_lds16(const float* g, float* s) {
    __builtin_amdgcn_global_load_lds(
        (const __attribute__((address_space(1))) unsigned int*)g,
        (__attribute__((address_space(3))) unsigned int*)s, 16, 0, 0);
}

// ---------------- pre-kernel: split W1 into padded bf16 hi/lo [NP][KP] ----------------
__global__ __launch_bounds__(256) void split_w_kernel(
    const float* __restrict__ W1,
    unsigned short* __restrict__ Whi, unsigned short* __restrict__ Wlo)
{
    int i = blockIdx.x * 256 + threadIdx.x;
    if (i >= NP * KP) return;
    int n = i / KP, k = i % KP;
    float w = (n < D_DIM && k < D_DIM) ? W1[n * D_DIM + k] : 0.0f;
    unsigned short hb = f2bf_rne(w);
    float lo = w - bf2f(hb);
    Whi[i] = hb;
    Wlo[i] = f2bf_rne(lo);
}

// ---------------- Kernel A (MFMA v2): gload_lds f32 staging + in-reg hi/lo cvt ----------------
// Block = 64 rows, 4 waves; wave owns 32 output cols. Frag/CD layout verified R5-R7.
__global__ __launch_bounds__(TPB, 4) void gemm_relu_mfma(
    const float* __restrict__ x,
    const unsigned short* __restrict__ Whi, const unsigned short* __restrict__ Wlo,
    const float* __restrict__ b1, float* __restrict__ out_h)
{
    // union: phase 1-2 = x f32 [64][100] + 32-word zero tail (6432 w);
    //        phase 3+  = h^T f32 [100][PITCH] (6500 w)
    __shared__ __align__(16) float smem[6500];
    const int tid  = threadIdx.x;
    const int lane = tid & 63;
    const int wave = tid >> 6;
    const int rowBase = blockIdx.x * RPB;
    const float* xg = x + (size_t)rowBase * D_DIM;

    // ---- B fragments (registers, L2-hot) + bias ----
    const int bcol0 = wave * 32;
    const int bn  = lane & 15;
    const int bk  = (lane >> 4) * 8;
    bf16x8 bh[2][4], bl[2][4];
    #pragma unroll
    for (int ct = 0; ct < 2; ++ct) {
        int n = bcol0 + ct * 16 + bn;
        #pragma unroll
        for (int kt = 0; kt < 4; ++kt) {
            int off = n * KP + kt * 32 + bk;
            bh[ct][kt] = *reinterpret_cast<const bf16x8*>(Whi + off);
            bl[ct][kt] = *reinterpret_cast<const bf16x8*>(Wlo + off);
        }
    }
    float bias[2];
    #pragma unroll
    for (int ct = 0; ct < 2; ++ct) {
        int n = bcol0 + ct * 16 + bn;
        bias[ct] = (n < D_DIM) ? b1[n] : 0.0f;
    }

    // ---- stage x via global_load_lds (identity mapping; 1600 16B chunks) ----
    #pragma unroll
    for (int it = 0; it < 6; ++it) {
        int cbase = it * 256 + wave * 64;                  // wave-uniform chunk base
        load_lds16(xg + (size_t)(cbase + lane) * 4, smem + cbase * 4);
    }
    if (wave == 0) {
        int cbase = 1536;
        load_lds16(xg + (size_t)(cbase + lane) * 4, smem + cbase * 4);
    }
    if (tid < 32) smem[6400 + tid] = 0.0f;   // finite tail for row-63 kt=3 overread
    __syncthreads();   // compiler drains vmcnt(0) (incl. lds-DMA) before barrier

    // ---- MFMA main: per (rt,kt): LDS f32 read -> hi/lo cvt in-reg -> 6 MFMAs ----
    // A k>=100 is garbage-but-finite; B is zero there -> contributes exactly 0.
    const int am = lane & 15;
    const int ak = (lane >> 4) * 8;
    f32x4 acc[4][2];
    #pragma unroll
    for (int rt = 0; rt < 4; ++rt) {
        acc[rt][0] = (f32x4){0.f, 0.f, 0.f, 0.f};
        acc[rt][1] = (f32x4){0.f, 0.f, 0.f, 0.f};
    }
    #pragma unroll
    for (int rt = 0; rt < 4; ++rt) {
        const int rbase = (rt * 16 + am) * D_DIM;
        #pragma unroll
        for (int kt = 0; kt < 4; ++kt) {
            const float* p = smem + rbase + kt * 32 + ak;  // 16B-aligned
            f32x4 f0 = *reinterpret_cast<const f32x4*>(p);
            f32x4 f1 = *reinterpret_cast<const f32x4*>(p + 4);
            bf16x8 ah, al;
            #pragma unroll
            for (int i = 0; i < 4; ++i) {
                __bf16 h0 = (__bf16)f0[i];
                ah[i] = h0;
                al[i] = (__bf16)(f0[i] - (float)h0);
                __bf16 h1 = (__bf16)f1[i];
                ah[4 + i] = h1;
                al[4 + i] = (__bf16)(f1[i] - (float)h1);
            }
            // same pass order as R5-R7 (numerics preserved)
            acc[rt][0] = __builtin_amdgcn_mfma_f32_16x16x32_bf16(ah, bl[0][kt], acc[rt][0], 0, 0, 0);
            acc[rt][0] = __builtin_amdgcn_mfma_f32_16x16x32_bf16(al, bh[0][kt], acc[rt][0], 0, 0, 0);
            acc[rt][0] = __builtin_amdgcn_mfma_f32_16x16x32_bf16(ah, bh[0][kt], acc[rt][0], 0, 0, 0);
            acc[rt][1] = __builtin_amdgcn_mfma_f32_16x16x32_bf16(ah, bl[1][kt], acc[rt][1], 0, 0, 0);
            acc[rt][1] = __builtin_amdgcn_mfma_f32_16x16x32_bf16(al, bh[1][kt], acc[rt][1], 0, 0, 0);
            acc[rt][1] = __builtin_amdgcn_mfma_f32_16x16x32_bf16(ah, bh[1][kt], acc[rt][1], 0, 0, 0);
        }
    }
    __syncthreads();   // all staging-tile reads done -> safe to overwrite smem

    // ---- bias+ReLU epilogue into LDS h^T tile (conflict-free: pitch 65) ----
    #pragma unroll
    for (int rt = 0; rt < 4; ++rt) {
        int rb = rt * 16 + (lane >> 4) * 4;
        #pragma unroll
        for (int ct = 0; ct < 2; ++ct) {
            int n = bcol0 + ct * 16 + bn;
            if (n < D_DIM) {
                #pragma unroll
                for (int i = 0; i < 4; ++i)
                    smem[n * PITCH + rb + i] = fmaxf(acc[rt][ct][i] + bias[ct], 0.0f);
            }
        }
    }
    __syncthreads();

    // ---- coalesced float4 h writeout ----
    float* hg = out_h + (size_t)rowBase * D_DIM;
    for (int v = tid; v < RPB * 25; v += TPB) {
        int r = v / 25;
        int d = (v % 25) * 4;
        reinterpret_cast<float4*>(hg)[v] = make_float4(
            smem[d * PITCH + r], smem[(d + 1) * PITCH + r],
            smem[(d + 2) * PITCH + r], smem[(d + 3) * PITCH + r]);
    }
}

// ---------------- Kernel B: VQ with margin-guarded exact recompute (R6-proven) ----------------
__global__ __launch_bounds__(TPB) void vq_kernel(
    const float* __restrict__ h, const float* __restrict__ x,
    const float* __restrict__ W1, const float* __restrict__ b1,
    const float* __restrict__ cb, const int* __restrict__ qflag,
    float* __restrict__ out_pay, float* __restrict__ out_aux,
    double* __restrict__ partials)
{
    __shared__ float  tile[D_DIM][PITCH];
    __shared__ double d2s[K_CODES][RPB];
    __shared__ int    idxs[RPB];
    __shared__ unsigned long long flagmask;
    const int tid  = threadIdx.x;
    const int lane = tid & 63;
    const int wave = tid >> 6;
    const int blk  = blockIdx.x;
    const int rowBase = blk * RPB;
    const int qz = *qflag;

    if (qz) {
        const float* hgc = h + (size_t)rowBase * D_DIM;
        for (int v = tid; v < (RPB * D_DIM) / 4; v += TPB) {
            float4 val = reinterpret_cast<const float4*>(hgc)[v];
            int r = v / 25;
            int d = (v % 25) * 4;
            tile[d + 0][r] = val.x; tile[d + 1][r] = val.y;
            tile[d + 2][r] = val.z; tile[d + 3][r] = val.w;
        }
        __syncthreads();
        {   // wave = code k, lane = row; f64 distances
            const int k = __builtin_amdgcn_readfirstlane(wave & 3);
            const float* crow = cb + k * D_DIM;
            double s = 0.0;
            #pragma unroll
            for (int d = 0; d < D_DIM; ++d) {
                double dh = (double)tile[d][lane] - (double)crow[d];
                s = fma(dh, dh, s);
            }
            d2s[k][lane] = s;
        }
        __syncthreads();

        if (wave == 0) {   // tentative argmin + margin flag
            double best = d2s[0][lane], second = 1e300;
            int bi = 0;
            #pragma unroll
            for (int k = 1; k < K_CODES; ++k) {
                double v = d2s[k][lane];
                if (v < best) { second = best; best = v; bi = k; }
                else if (v < second) { second = v; }
            }
            idxs[lane] = bi;
            unsigned long long m = __ballot((second - best) < TAU);
            if (lane == 0) flagmask = m;
        }
        __syncthreads();

        {   // flagged rows: wave-cooperative exact recompute (R1 arithmetic)
            unsigned long long m = flagmask;
            int i = 0;
            while (m) {
                int r = __ffsll((long long)m) - 1;
                m &= m - 1;
                if ((i & 3) == wave) {
                    const int e1 = lane;
                    const int e2 = 64 + lane;
                    const bool has2 = (e2 < D_DIM);
                    float z1 = b1[e1];
                    float z2 = has2 ? b1[e2] : 0.0f;
                    const float* xr  = x + (size_t)(rowBase + r) * D_DIM;
                    const float* w1r = W1 + e1 * D_DIM;
                    const float* w2r = W1 + (has2 ? e2 : 0) * D_DIM;
                    #pragma unroll
                    for (int d4 = 0; d4 < 25; ++d4) {
                        float4 xv = reinterpret_cast<const float4*>(xr)[d4];
                        float4 wa = reinterpret_cast<const float4*>(w1r)[d4];
                        z1 = fmaf(xv.x, wa.x, z1); z1 = fmaf(xv.y, wa.y, z1);
                        z1 = fmaf(xv.z, wa.z, z1); z1 = fmaf(xv.w, wa.w, z1);
                        float4 wb = reinterpret_cast<const float4*>(w2r)[d4];
                        z2 = fmaf(xv.x, wb.x, z2); z2 = fmaf(xv.y, wb.y, z2);
                        z2 = fmaf(xv.z, wb.z, z2); z2 = fmaf(xv.w, wb.w, z2);
                    }
                    float h1 = fmaxf(z1, 0.0f);
                    float h2 = fmaxf(z2, 0.0f);
                    double dk[K_CODES];
                    #pragma unroll
                    for (int k = 0; k < K_CODES; ++k) {
                        double p;
                        {
                            double dh = (double)h1 - (double)cb[k * D_DIM + e1];
                            p = dh * dh;
                        }
                        if (has2) {
                            double dh = (double)h2 - (double)cb[k * D_DIM + e2];
                            p = fma(dh, dh, p);
                        }
                        for (int off = 32; off > 0; off >>= 1)
                            p += __shfl_down(p, off);
                        dk[k] = p;
                    }
                    if (lane == 0) {
                        double best = dk[0];
                        int bi = 0;
                        #pragma unroll
                        for (int k = 1; k < K_CODES; ++k)
                            if (dk[k] < best) { best = dk[k]; bi = k; }
                        idxs[r] = bi;
                    }
                }
                ++i;
            }
        }
        __syncthreads();

        if (wave == 0) {   // payload + loss partial
            int bi = idxs[lane];
            out_pay[rowBase + lane] = (float)bi;
            double d2min = d2s[bi][lane];
            for (int off = 32; off > 0; off >>= 1)
                d2min += __shfl_down(d2min, off);
            if (lane == 0) partials[blk] = d2min;
        }

        float* ag = out_aux + (size_t)rowBase * D_DIM;
        for (int v = tid; v < (RPB * D_DIM) / 4; v += TPB) {
            int r = v / 25;
            int d = (v % 25) * 4;
            int bi = idxs[r];
            reinterpret_cast<float4*>(ag)[v] =
                reinterpret_cast<const float4*>(cb + bi * D_DIM + d)[0];
        }
    } else {
        if (wave == 0) {
            out_pay[rowBase + lane] = 0.0f;
            if (lane == 0) partials[blk] = 0.0;
        }
        float* ag = out_aux + (size_t)rowBase * D_DIM;
        for (int v = tid; v < (RPB * D_DIM) / 4; v += TPB)
            reinterpret_cast<float4*>(ag)[v] = make_float4(0, 0, 0, 0);
    }
}

// ---------------- deterministic final loss reduce ----------------
__global__ __launch_bounds__(256) void vq_final_kernel(
    const double* __restrict__ partials, int n, float* __restrict__ loss_out)
{
    __shared__ double sm[256];
    int tid = threadIdx.x;
    double s = 0.0;
    for (int i = tid; i < n; i += 256) s += partials[i];
    sm[tid] = s;
    __syncthreads();
    for (int off = 128; off > 0; off >>= 1) {
        if (tid < off) sm[tid] += sm[tid + off];
        __syncthreads();
    }
    if (tid == 0) {
        double mse = sm[0] / ((double)N_ROWS * (double)D_DIM);
        loss_out[0] = (float)(1.25 * mse);   // (1 + BETA) * mean((h-q)^2)
    }
}

extern "C" void kernel_launch(void* const* d_in, const int* in_sizes, int n_in,
                              void* d_out, int out_size, void* d_ws, size_t ws_size,
                              hipStream_t stream) {
    const float* x  = (const float*)d_in[0];
    const float* W1 = (const float*)d_in[1];
    const float* b1 = (const float*)d_in[2];
    const float* cb = (const float*)d_in[3];
    const int* qflag = (const int*)d_in[4];

    float* out = (float*)d_out;
    const int NR = in_sizes[0] / D_DIM;        // 262144 rows
    const int nblocks = NR / RPB;              // 4096

    float* out_h    = out;                                  // [NR*100]
    float* out_pay  = out + (size_t)NR * D_DIM;             // [NR]
    float* out_aux  = out_pay + NR;                         // [NR*100]
    float* out_loss = out_aux + (size_t)NR * D_DIM;         // [1]

    double* partials = (double*)d_ws;                       // 32 KB
    const size_t w_off = (size_t)nblocks * sizeof(double);
    unsigned short* Whi = (unsigned short*)((char*)d_ws + w_off);   // 32 KB
    unsigned short* Wlo = Whi + NP * KP;                            // 32 KB

    split_w_kernel<<<(NP * KP) / 256, 256, 0, stream>>>(W1, Whi, Wlo);
    gemm_relu_mfma<<<nblocks, TPB, 0, stream>>>(x, Whi, Wlo, b1, out_h);
    vq_kernel<<<nblocks, TPB, 0, stream>>>(out_h, x, W1, b1, cb, qflag,
                                           out_pay, out_aux, partials);
    vq_final_kernel<<<1, 256, 0, stream>>>(partials, nblocks, out_loss);
}

// Round 9
// 117.596 us; speedup vs baseline: 1.4426x; 1.0833x over previous
//
#include <hip/hip_runtime.h>

// Problem constants (B=64, T=4096, D=100, K=4, BETA=0.25)
#define D_DIM   100
#define K_CODES 4
#define RPB     64      // rows per tile
#define TPB     256     // threads per block (4 waves)
#define PITCH   65      // f32 h^T-tile pitch (words)
#define N_ROWS  262144  // B*T
#define KP      128     // padded K for W hi/lo storage (4 k-tiles of 32)
#define NP      128     // padded N rows of W hi/lo storage
#define TAU     0.25    // d2 margin below which we recompute exactly
#define GRID_GEMM 1024  // gemm blocks; each handles 4 tiles (4096 total)
#define NTILES  4

typedef __attribute__((ext_vector_type(8))) __bf16 bf16x8;
typedef __attribute__((ext_vector_type(4))) float  f32x4;

__device__ __forceinline__ unsigned short f2bf_rne(float f) {
    unsigned int u = __builtin_bit_cast(unsigned int, f);
    unsigned int r = u + 0x7fffu + ((u >> 16) & 1u);
    return (unsigned short)(r >> 16);
}
__device__ __forceinline__ float bf2f(unsigned short b) {
    unsigned int u = ((unsigned int)b) << 16;
    return __builtin_bit_cast(float, u);
}

// async global->LDS, 16B per lane: LDS dest = wave-uniform base + lane*16
__device__ __forceinline__ void load_lds16(const float* g, float* s) {
    __builtin_amdgcn_global_load_lds(
        (const __attribute__((address_space(1))) unsigned int*)g,
        (__attribute__((address_space(3))) unsigned int*)s, 16, 0, 0);
}

// stage one 64x100 f32 x-tile (1600 16B chunks) into LDS
__device__ __forceinline__ void stage_x(const float* xg, float* s, int wave, int lane) {
    #pragma unroll
    for (int it = 0; it < 6; ++it) {
        int cbase = it * 256 + wave * 64;                  // wave-uniform chunk base
        load_lds16(xg + (size_t)(cbase + lane) * 4, s + cbase * 4);
    }
    if (wave == 0) load_lds16(xg + (size_t)(1536 + lane) * 4, s + 1536 * 4);
}

// ---------------- pre-kernel: split W1 into padded bf16 hi/lo [NP][KP] ----------------
__global__ __launch_bounds__(256) void split_w_kernel(
    const float* __restrict__ W1,
    unsigned short* __restrict__ Whi, unsigned short* __restrict__ Wlo)
{
    int i = blockIdx.x * 256 + threadIdx.x;
    if (i >= NP * KP) return;
    int n = i / KP, k = i % KP;
    float w = (n < D_DIM && k < D_DIM) ? W1[n * D_DIM + k] : 0.0f;
    unsigned short hb = f2bf_rne(w);
    float lo = w - bf2f(hb);
    Whi[i] = hb;
    Wlo[i] = f2bf_rne(lo);
}

// ---------------- Kernel A (MFMA v3): 4 tiles/block, dbuf gload_lds staging ----------------
// Per tile: 64 rows, wave owns 32 output cols. Frag/CD layout + numerics identical to R8.
__global__ __launch_bounds__(TPB, 4) void gemm_relu_mfma(
    const float* __restrict__ x,
    const unsigned short* __restrict__ Whi, const unsigned short* __restrict__ Wlo,
    const float* __restrict__ b1, float* __restrict__ out_h)
{
    // two buffers: x f32 tile [64][100] + 32-word tail, reused as h^T [100][65] after compute
    __shared__ __align__(16) float buf0[6500];
    __shared__ __align__(16) float buf1[6500];
    const int tid  = threadIdx.x;
    const int lane = tid & 63;
    const int wave = tid >> 6;

    // ---- B fragments + bias: loaded ONCE per block (amortized over 4 tiles) ----
    const int bcol0 = wave * 32;
    const int bn  = lane & 15;
    const int bk  = (lane >> 4) * 8;
    bf16x8 bh[2][4], bl[2][4];
    #pragma unroll
    for (int ct = 0; ct < 2; ++ct) {
        int n = bcol0 + ct * 16 + bn;
        #pragma unroll
        for (int kt = 0; kt < 4; ++kt) {
            int off = n * KP + kt * 32 + bk;
            bh[ct][kt] = *reinterpret_cast<const bf16x8*>(Whi + off);
            bl[ct][kt] = *reinterpret_cast<const bf16x8*>(Wlo + off);
        }
    }
    float bias[2];
    #pragma unroll
    for (int ct = 0; ct < 2; ++ct) {
        int n = bcol0 + ct * 16 + bn;
        bias[ct] = (n < D_DIM) ? b1[n] : 0.0f;
    }

    // zero overread tails once; afterwards tails only ever hold finite h values (x0 = exact 0 vs B zero-pad)
    if (tid < 32) { buf0[6400 + tid] = 0.0f; buf1[6400 + tid] = 0.0f; }

    // prologue: stage tile 0 into buf0
    stage_x(x + (size_t)blockIdx.x * RPB * D_DIM, buf0, wave, lane);

    const int am = lane & 15;
    const int ak = (lane >> 4) * 8;

    for (int it = 0; it < NTILES; ++it) {
        const int tile = blockIdx.x + it * GRID_GEMM;
        const int rowBase = tile * RPB;
        float* cur = (it & 1) ? buf1 : buf0;
        float* nxt = (it & 1) ? buf0 : buf1;

        __syncthreads();   // staging of cur drained; prev tile's writeout reads of nxt done

        if (it + 1 < NTILES)   // prefetch next tile; hides under MFMA phase
            stage_x(x + (size_t)(blockIdx.x + (it + 1) * GRID_GEMM) * RPB * D_DIM,
                    nxt, wave, lane);

        // ---- MFMA: per (rt,kt): LDS f32 read -> in-reg hi/lo cvt -> 6 MFMAs ----
        f32x4 acc[4][2];
        #pragma unroll
        for (int rt = 0; rt < 4; ++rt) {
            acc[rt][0] = (f32x4){0.f, 0.f, 0.f, 0.f};
            acc[rt][1] = (f32x4){0.f, 0.f, 0.f, 0.f};
        }
        #pragma unroll
        for (int rt = 0; rt < 4; ++rt) {
            const int rbase = (rt * 16 + am) * D_DIM;
            #pragma unroll
            for (int kt = 0; kt < 4; ++kt) {
                const float* p = cur + rbase + kt * 32 + ak;   // 16B-aligned
                f32x4 f0 = *reinterpret_cast<const f32x4*>(p);
                f32x4 f1 = *reinterpret_cast<const f32x4*>(p + 4);
                bf16x8 ah, al;
                #pragma unroll
                for (int i = 0; i < 4; ++i) {
                    __bf16 h0 = (__bf16)f0[i];
                    ah[i] = h0;
                    al[i] = (__bf16)(f0[i] - (float)h0);
                    __bf16 h1 = (__bf16)f1[i];
                    ah[4 + i] = h1;
                    al[4 + i] = (__bf16)(f1[i] - (float)h1);
                }
                // exact same pass order as R5-R8 (numerics preserved)
                acc[rt][0] = __builtin_amdgcn_mfma_f32_16x16x32_bf16(ah, bl[0][kt], acc[rt][0], 0, 0, 0);
                acc[rt][0] = __builtin_amdgcn_mfma_f32_16x16x32_bf16(al, bh[0][kt], acc[rt][0], 0, 0, 0);
                acc[rt][0] = __builtin_amdgcn_mfma_f32_16x16x32_bf16(ah, bh[0][kt], acc[rt][0], 0, 0, 0);
                acc[rt][1] = __builtin_amdgcn_mfma_f32_16x16x32_bf16(ah, bl[1][kt], acc[rt][1], 0, 0, 0);
                acc[rt][1] = __builtin_amdgcn_mfma_f32_16x16x32_bf16(al, bh[1][kt], acc[rt][1], 0, 0, 0);
                acc[rt][1] = __builtin_amdgcn_mfma_f32_16x16x32_bf16(ah, bh[1][kt], acc[rt][1], 0, 0, 0);
            }
        }
        __syncthreads();   // cur reads done -> safe to overwrite with h^T (prefetch drains too; it had the MFMA phase to fly)

        // ---- bias+ReLU epilogue into cur as h^T [100][65] ----
        #pragma unroll
        for (int rt = 0; rt < 4; ++rt) {
            int rb = rt * 16 + (lane >> 4) * 4;
            #pragma unroll
            for (int ct = 0; ct < 2; ++ct) {
                int n = bcol0 + ct * 16 + bn;
                if (n < D_DIM) {
                    #pragma unroll
                    for (int i = 0; i < 4; ++i)
                        cur[n * PITCH + rb + i] = fmaxf(acc[rt][ct][i] + bias[ct], 0.0f);
                }
            }
        }
        __syncthreads();

        // ---- coalesced float4 h writeout ----
        float* hg = out_h + (size_t)rowBase * D_DIM;
        for (int v = tid; v < RPB * 25; v += TPB) {
            int r = v / 25;
            int d = (v % 25) * 4;
            reinterpret_cast<float4*>(hg)[v] = make_float4(
                cur[d * PITCH + r], cur[(d + 1) * PITCH + r],
                cur[(d + 2) * PITCH + r], cur[(d + 3) * PITCH + r]);
        }
    }
}

// ---------------- Kernel B: VQ with margin-guarded exact recompute (R6-proven) ----------------
__global__ __launch_bounds__(TPB) void vq_kernel(
    const float* __restrict__ h, const float* __restrict__ x,
    const float* __restrict__ W1, const float* __restrict__ b1,
    const float* __restrict__ cb, const int* __restrict__ qflag,
    float* __restrict__ out_pay, float* __restrict__ out_aux,
    double* __restrict__ partials)
{
    __shared__ float  tile[D_DIM][PITCH];
    __shared__ double d2s[K_CODES][RPB];
    __shared__ int    idxs[RPB];
    __shared__ unsigned long long flagmask;
    const int tid  = threadIdx.x;
    const int lane = tid & 63;
    const int wave = tid >> 6;
    const int blk  = blockIdx.x;
    const int rowBase = blk * RPB;
    const int qz = *qflag;

    if (qz) {
        const float* hgc = h + (size_t)rowBase * D_DIM;
        for (int v = tid; v < (RPB * D_DIM) / 4; v += TPB) {
            float4 val = reinterpret_cast<const float4*>(hgc)[v];
            int r = v / 25;
            int d = (v % 25) * 4;
            tile[d + 0][r] = val.x; tile[d + 1][r] = val.y;
            tile[d + 2][r] = val.z; tile[d + 3][r] = val.w;
        }
        __syncthreads();
        {   // wave = code k, lane = row; f64 distances
            const int k = __builtin_amdgcn_readfirstlane(wave & 3);
            const float* crow = cb + k * D_DIM;
            double s = 0.0;
            #pragma unroll
            for (int d = 0; d < D_DIM; ++d) {
                double dh = (double)tile[d][lane] - (double)crow[d];
                s = fma(dh, dh, s);
            }
            d2s[k][lane] = s;
        }
        __syncthreads();

        if (wave == 0) {   // tentative argmin + margin flag
            double best = d2s[0][lane], second = 1e300;
            int bi = 0;
            #pragma unroll
            for (int k = 1; k < K_CODES; ++k) {
                double v = d2s[k][lane];
                if (v < best) { second = best; best = v; bi = k; }
                else if (v < second) { second = v; }
            }
            idxs[lane] = bi;
            unsigned long long m = __ballot((second - best) < TAU);
            if (lane == 0) flagmask = m;
        }
        __syncthreads();

        {   // flagged rows: wave-cooperative exact recompute (R1 arithmetic)
            unsigned long long m = flagmask;
            int i = 0;
            while (m) {
                int r = __ffsll((long long)m) - 1;
                m &= m - 1;
                if ((i & 3) == wave) {
                    const int e1 = lane;
                    const int e2 = 64 + lane;
                    const bool has2 = (e2 < D_DIM);
                    float z1 = b1[e1];
                    float z2 = has2 ? b1[e2] : 0.0f;
                    const float* xr  = x + (size_t)(rowBase + r) * D_DIM;
                    const float* w1r = W1 + e1 * D_DIM;
                    const float* w2r = W1 + (has2 ? e2 : 0) * D_DIM;
                    #pragma unroll
                    for (int d4 = 0; d4 < 25; ++d4) {
                        float4 xv = reinterpret_cast<const float4*>(xr)[d4];
                        float4 wa = reinterpret_cast<const float4*>(w1r)[d4];
                        z1 = fmaf(xv.x, wa.x, z1); z1 = fmaf(xv.y, wa.y, z1);
                        z1 = fmaf(xv.z, wa.z, z1); z1 = fmaf(xv.w, wa.w, z1);
                        float4 wb = reinterpret_cast<const float4*>(w2r)[d4];
                        z2 = fmaf(xv.x, wb.x, z2); z2 = fmaf(xv.y, wb.y, z2);
                        z2 = fmaf(xv.z, wb.z, z2); z2 = fmaf(xv.w, wb.w, z2);
                    }
                    float h1 = fmaxf(z1, 0.0f);
                    float h2 = fmaxf(z2, 0.0f);
                    double dk[K_CODES];
                    #pragma unroll
                    for (int k = 0; k < K_CODES; ++k) {
                        double p;
                        {
                            double dh = (double)h1 - (double)cb[k * D_DIM + e1];
                            p = dh * dh;
                        }
                        if (has2) {
                            double dh = (double)h2 - (double)cb[k * D_DIM + e2];
                            p = fma(dh, dh, p);
                        }
                        for (int off = 32; off > 0; off >>= 1)
                            p += __shfl_down(p, off);
                        dk[k] = p;
                    }
                    if (lane == 0) {
                        double best = dk[0];
                        int bi = 0;
                        #pragma unroll
                        for (int k = 1; k < K_CODES; ++k)
                            if (dk[k] < best) { best = dk[k]; bi = k; }
                        idxs[r] = bi;
                    }
                }
                ++i;
            }
        }
        __syncthreads();

        if (wave == 0) {   // payload + loss partial
            int bi = idxs[lane];
            out_pay[rowBase + lane] = (float)bi;
            double d2min = d2s[bi][lane];
            for (int off = 32; off > 0; off >>= 1)
                d2min += __shfl_down(d2min, off);
            if (lane == 0) partials[blk] = d2min;
        }

        float* ag = out_aux + (size_t)rowBase * D_DIM;
        for (int v = tid; v < (RPB * D_DIM) / 4; v += TPB) {
            int r = v / 25;
            int d = (v % 25) * 4;
            int bi = idxs[r];
            reinterpret_cast<float4*>(ag)[v] =
                reinterpret_cast<const float4*>(cb + bi * D_DIM + d)[0];
        }
    } else {
        if (wave == 0) {
            out_pay[rowBase + lane] = 0.0f;
            if (lane == 0) partials[blk] = 0.0;
        }
        float* ag = out_aux + (size_t)rowBase * D_DIM;
        for (int v = tid; v < (RPB * D_DIM) / 4; v += TPB)
            reinterpret_cast<float4*>(ag)[v] = make_float4(0, 0, 0, 0);
    }
}

// ---------------- deterministic final loss reduce ----------------
__global__ __launch_bounds__(256) void vq_final_kernel(
    const double* __restrict__ partials, int n, float* __restrict__ loss_out)
{
    __shared__ double sm[256];
    int tid = threadIdx.x;
    double s = 0.0;
    for (int i = tid; i < n; i += 256) s += partials[i];
    sm[tid] = s;
    __syncthreads();
    for (int off = 128; off > 0; off >>= 1) {
        if (tid < off) sm[tid] += sm[tid + off];
        __syncthreads();
    }
    if (tid == 0) {
        double mse = sm[0] / ((double)N_ROWS * (double)D_DIM);
        loss_out[0] = (float)(1.25 * mse);   // (1 + BETA) * mean((h-q)^2)
    }
}

extern "C" void kernel_launch(void* const* d_in, const int* in_sizes, int n_in,
                              void* d_out, int out_size, void* d_ws, size_t ws_size,
                              hipStream_t stream) {
    const float* x  = (const float*)d_in[0];
    const float* W1 = (const float*)d_in[1];
    const float* b1 = (const float*)d_in[2];
    const float* cb = (const float*)d_in[3];
    const int* qflag = (const int*)d_in[4];

    float* out = (float*)d_out;
    const int NR = in_sizes[0] / D_DIM;        // 262144 rows
    const int nblocks = NR / RPB;              // 4096 tiles

    float* out_h    = out;                                  // [NR*100]
    float* out_pay  = out + (size_t)NR * D_DIM;             // [NR]
    float* out_aux  = out_pay + NR;                         // [NR*100]
    float* out_loss = out_aux + (size_t)NR * D_DIM;         // [1]

    double* partials = (double*)d_ws;                       // 32 KB
    const size_t w_off = (size_t)nblocks * sizeof(double);
    unsigned short* Whi = (unsigned short*)((char*)d_ws + w_off);   // 32 KB
    unsigned short* Wlo = Whi + NP * KP;                            // 32 KB

    split_w_kernel<<<(NP * KP) / 256, 256, 0, stream>>>(W1, Whi, Wlo);
    gemm_relu_mfma<<<GRID_GEMM, TPB, 0, stream>>>(x, Whi, Wlo, b1, out_h);
    vq_kernel<<<nblocks, TPB, 0, stream>>>(out_h, x, W1, b1, cb, qflag,
                                           out_pay, out_aux, partials);
    vq_final_kernel<<<1, 256, 0, stream>>>(partials, nblocks, out_loss);
}